// Round 1
// baseline (1015.015 us; speedup 1.0000x reference)
//
#include <hip/hip_runtime.h>

// ---------------------------------------------------------------------------
// StructuralCausalModel: 3 layers x 32 vars sequential scan, BATCH=512.
// Strategy: batch rows are independent -> 64 persistent blocks, 8 rows each,
// run all 96 steps privately. bf16 MFMA 16x16x32 for the 4 GEMMs, VALU for
// the adjacency-weighted reduce. Weights pre-swizzled to MFMA-B frag order.
// ---------------------------------------------------------------------------

typedef __bf16 bf16x8 __attribute__((ext_vector_type(8)));
typedef float  f32x4  __attribute__((ext_vector_type(4)));

#define N_VARS 32
#define D_MODEL 256
#define D_MECH 128
#define D_NOISE 64
#define BATCH 512
#define NBLK 64          // 512 / 8 rows per block
#define BTILE 8

// ws element offsets (bf16 region starts at byte 4096; adj f32 at byte 0)
#define ELOFF_PA 0
#define ELOFF_W1 65536          // 16nt*8ks*64lane*8 = 65536 el
#define ELOFF_W2 1114112        // + 32*8*8*64*8
#define ELOFF_W3 1638400        // + 32*8*4*64*8
#define ELOFF_VALS 2686976      // + 32*16*4*64*8
// total bf16 el = 2686976 + 64*65536 = 6881280 -> ws bytes = 4096 + 13762560

__device__ __forceinline__ unsigned short f2b(float f) {
    unsigned u = __float_as_uint(f);
    u += 0x7FFFu + ((u >> 16) & 1u);
    return (unsigned short)(u >> 16);
}
__device__ __forceinline__ float b2f(unsigned u16) {
    return __uint_as_float(u16 << 16);
}

// exact-erf GELU via Abramowitz-Stegun 7.1.26 (|err| <= 1.5e-7)
__device__ __forceinline__ float gelu_exact(float x) {
    float z  = x * 0.7071067811865476f;
    float az = fabsf(z);
    float t  = 1.0f / (1.0f + 0.3275911f * az);
    float p  = t * (0.254829592f + t * (-0.284496736f + t * (1.421413741f +
               t * (-1.453152027f + t * 1.061405429f))));
    float e  = 1.0f - p * __expf(-z * z);
    float er = (z < 0.0f) ? -e : e;
    return 0.5f * x * (1.0f + er);
}

// ---------------------------------------------------------------------------
// Prep 1: convert all GEMM weights f32->bf16 pre-swizzled into MFMA-B fragment
// order; also compute adjacency = sigmoid(2 * masked_logits).
// B-frag (16x16x32): lane l, elem j -> k = ks*32 + (l>>4)*8 + j, n = nt*16 + (l&15)
// frag linear index within a weight: (nt*KS + ks)*64 + lane
// ---------------------------------------------------------------------------
__global__ void prep_w(const float* __restrict__ paW, const float* __restrict__ mW1,
                       const float* __restrict__ mW2, const float* __restrict__ mW3,
                       const float* __restrict__ edge, unsigned short* __restrict__ wsb,
                       float* __restrict__ adjw) {
    int idx = blockIdx.x * 256 + threadIdx.x;
    if (idx < 335872) {
        const float* src; int n, kb, N;
        int f = idx;
        if (f < 8192) {                       // pa_W: 16nt x 8ks
            int nt = f >> 9, ks = (f >> 6) & 7, lane = f & 63;
            n = nt * 16 + (lane & 15); kb = ks * 32 + ((lane >> 4) << 3);
            src = paW; N = 256;
        } else if (f < 139264) {              // m_W1: per var 8nt x 8ks
            int f1 = f - 8192; int var = f1 >> 12; int r = f1 & 4095;
            int nt = r >> 9, ks = (r >> 6) & 7, lane = r & 63;
            n = nt * 16 + (lane & 15); kb = ks * 32 + ((lane >> 4) << 3);
            src = mW1 + var * 32768; N = 128;
        } else if (f < 204800) {              // m_W2: per var 8nt x 4ks
            int f2 = f - 139264; int var = f2 >> 11; int r = f2 & 2047;
            int nt = r >> 8, ks = (r >> 6) & 3, lane = r & 63;
            n = nt * 16 + (lane & 15); kb = ks * 32 + ((lane >> 4) << 3);
            src = mW2 + var * 16384; N = 128;
        } else {                               // m_W3: per var 16nt x 4ks
            int f3 = f - 204800; int var = f3 >> 12; int r = f3 & 4095;
            int nt = r >> 8, ks = (r >> 6) & 3, lane = r & 63;
            n = nt * 16 + (lane & 15); kb = ks * 32 + ((lane >> 4) << 3);
            src = mW3 + var * 32768; N = 256;
        }
        unsigned o[8];
        #pragma unroll
        for (int j = 0; j < 8; j++) o[j] = f2b(src[(kb + j) * N + n]);
        uint4 pk;
        pk.x = o[0] | (o[1] << 16); pk.y = o[2] | (o[3] << 16);
        pk.z = o[4] | (o[5] << 16); pk.w = o[6] | (o[7] << 16);
        *(uint4*)(wsb + (size_t)f * 8) = pk;
    } else if (idx < 336896) {
        int t = idx - 335872; int v = t >> 5; int c = t & 31;
        float x = edge[t];
        float m = (v == c) ? 0.0f : x;        // diag masked BEFORE sigmoid -> diag=0.5
        adjw[t] = 1.0f / (1.0f + __expf(-2.0f * m));   // /TEMP(0.5) == *2
    }
}

// ---------------------------------------------------------------------------
// Prep 2: noise encoder NE[b,i,:] = gelu(noise[b,i,:] @ ne_W[i] + ne_b[i]),
// layer-invariant -> compute once, store f32 into d_out (same shape; real
// output overwrites it at layer 2).
// grid: 32 vars x 8 batch-groups of 64; thread = output feature d.
// ---------------------------------------------------------------------------
__global__ void prep_ne(const float* __restrict__ noise, const float* __restrict__ neW,
                        const float* __restrict__ neb, float* __restrict__ outp) {
    int i = blockIdx.x >> 3, g = blockIdx.x & 7, d = threadIdx.x;
    float w[64];
    #pragma unroll
    for (int k = 0; k < 64; k++) w[k] = neW[(i * 64 + k) * 256 + d];
    float bias = neb[i * 256 + d];
    for (int bb = 0; bb < 64; bb++) {
        int b = g * 64 + bb;
        const float* nr = noise + (b * 32 + i) * 64;   // block-uniform -> s_load
        float acc = bias;
        #pragma unroll
        for (int k = 0; k < 64; k++) acc += nr[k] * w[k];
        outp[(b * 32 + i) * 256 + d] = gelu_exact(acc);
    }
}

// ---------------------------------------------------------------------------
// Main: 64 blocks x 512 threads (8 waves). Each block owns 8 batch rows and a
// private bf16 values buffer [32 var][8 b][256 d] in ws (L2-resident).
// Per step: pc (VALU) -> pa -> W1 -> W2 -> W3 (+bias +NE), 5 barriers.
// MFMA tiles padded to M=16; rows 8..15 of LDS activation buffers stay zero.
// ---------------------------------------------------------------------------
__global__ __launch_bounds__(512) void
scm_main(const float* __restrict__ emb, const float* __restrict__ pab,
         const float* __restrict__ mb1, const float* __restrict__ mb2,
         const float* __restrict__ mb3, const float* __restrict__ adjw,
         const __bf16* __restrict__ wsbf, float* __restrict__ outp,
         unsigned short* __restrict__ valsAll) {
    __shared__ unsigned short Xs[16 * 264];   // pc+emb  (A for pa)
    __shared__ unsigned short X2[16 * 264];   // parent_input (A for W1)
    __shared__ unsigned short Hs1[16 * 136];  // h1 (A for W2)
    __shared__ unsigned short Hs2[16 * 136];  // h2 (A for W3)
    __shared__ float acol[32];

    const int tid = threadIdx.x, blk = blockIdx.x;
    unsigned short* vals = valsAll + (size_t)blk * 65536;

    // zero LDS pads + private values (ws is poisoned 0xAA every launch)
    for (int k = tid; k < 16 * 264; k += 512) { Xs[k] = 0; X2[k] = 0; }
    for (int k = tid; k < 16 * 136; k += 512) { Hs1[k] = 0; Hs2[k] = 0; }
    {
        uint4 z; z.x = z.y = z.z = z.w = 0;
        for (int k = tid; k < 8192; k += 512) ((uint4*)vals)[k] = z;
    }
    __syncthreads();

    const __bf16* wsPA = wsbf + ELOFF_PA;
    const __bf16* wsW1 = wsbf + ELOFF_W1;
    const __bf16* wsW2 = wsbf + ELOFF_W2;
    const __bf16* wsW3 = wsbf + ELOFF_W3;

    const int wid = tid >> 6, lane = tid & 63, l15 = lane & 15, q = lane >> 4;

    for (int layer = 0; layer < 3; layer++) {
        for (int i = 0; i < N_VARS; i++) {
            if (tid < 32) acol[tid] = adjw[tid * 32 + i];
            __syncthreads();

            // ---- pc = sum_v adj[v,i]*values[b,v,:]; X = bf16(pc + emb_i) ----
            {
                const int b = tid >> 6;
                const int d4 = lane << 2;
                float a0 = 0.f, a1 = 0.f, a2 = 0.f, a3 = 0.f;
                const unsigned short* vp = vals + b * 256 + d4;
                #pragma unroll
                for (int v = 0; v < 32; v++) {
                    uint2 u = *(const uint2*)(vp + v * 2048);
                    float s = acol[v];
                    a0 += s * b2f(u.x & 0xFFFFu); a1 += s * b2f(u.x >> 16);
                    a2 += s * b2f(u.y & 0xFFFFu); a3 += s * b2f(u.y >> 16);
                }
                const float4 e = *(const float4*)(emb + i * 256 + d4);
                uint2 w;
                w.x = (unsigned)f2b(a0 + e.x) | ((unsigned)f2b(a1 + e.y) << 16);
                w.y = (unsigned)f2b(a2 + e.z) | ((unsigned)f2b(a3 + e.w) << 16);
                *(uint2*)(Xs + b * 264 + d4) = w;
            }
            __syncthreads();

            // ---- parent_input = gelu(X @ pa_W + pa_b)  (N=256, K=256) ----
            {
                f32x4 acc0 = {0, 0, 0, 0}, acc1 = {0, 0, 0, 0};
                const int nt0 = wid, nt1 = wid + 8;
                #pragma unroll
                for (int ks = 0; ks < 8; ks++) {
                    bf16x8 af = *(const bf16x8*)(Xs + l15 * 264 + ks * 32 + q * 8);
                    bf16x8 b0 = *(const bf16x8*)(wsPA + ((nt0 * 8 + ks) * 64 + lane) * 8);
                    bf16x8 b1 = *(const bf16x8*)(wsPA + ((nt1 * 8 + ks) * 64 + lane) * 8);
                    acc0 = __builtin_amdgcn_mfma_f32_16x16x32_bf16(af, b0, acc0, 0, 0, 0);
                    acc1 = __builtin_amdgcn_mfma_f32_16x16x32_bf16(af, b1, acc1, 0, 0, 0);
                }
                #pragma unroll
                for (int r = 0; r < 4; r++) {
                    int mrow = q * 4 + r;
                    if (mrow < BTILE) {
                        int n0 = nt0 * 16 + l15, n1 = nt1 * 16 + l15;
                        X2[mrow * 264 + n0] = f2b(gelu_exact(acc0[r] + pab[n0]));
                        X2[mrow * 264 + n1] = f2b(gelu_exact(acc1[r] + pab[n1]));
                    }
                }
            }
            __syncthreads();

            // ---- h1 = gelu(X2 @ W1 + b1)  (N=128, K=256) ----
            {
                f32x4 acc = {0, 0, 0, 0};
                #pragma unroll
                for (int ks = 0; ks < 8; ks++) {
                    bf16x8 af = *(const bf16x8*)(X2 + l15 * 264 + ks * 32 + q * 8);
                    bf16x8 bf = *(const bf16x8*)(wsW1 + (size_t)i * 32768 +
                                                 ((wid * 8 + ks) * 64 + lane) * 8);
                    acc = __builtin_amdgcn_mfma_f32_16x16x32_bf16(af, bf, acc, 0, 0, 0);
                }
                #pragma unroll
                for (int r = 0; r < 4; r++) {
                    int mrow = q * 4 + r;
                    if (mrow < BTILE) {
                        int n = wid * 16 + l15;
                        Hs1[mrow * 136 + n] = f2b(gelu_exact(acc[r] + mb1[i * 128 + n]));
                    }
                }
            }
            __syncthreads();

            // ---- h2 = gelu(h1 @ W2 + b2)  (N=128, K=128) ----
            {
                f32x4 acc = {0, 0, 0, 0};
                #pragma unroll
                for (int ks = 0; ks < 4; ks++) {
                    bf16x8 af = *(const bf16x8*)(Hs1 + l15 * 136 + ks * 32 + q * 8);
                    bf16x8 bf = *(const bf16x8*)(wsW2 + (size_t)i * 16384 +
                                                 ((wid * 4 + ks) * 64 + lane) * 8);
                    acc = __builtin_amdgcn_mfma_f32_16x16x32_bf16(af, bf, acc, 0, 0, 0);
                }
                #pragma unroll
                for (int r = 0; r < 4; r++) {
                    int mrow = q * 4 + r;
                    if (mrow < BTILE) {
                        int n = wid * 16 + l15;
                        Hs2[mrow * 136 + n] = f2b(gelu_exact(acc[r] + mb2[i * 128 + n]));
                    }
                }
            }
            __syncthreads();

            // ---- out = h2 @ W3 + b3 + NE; values[:,i] = out ----
            {
                f32x4 acc0 = {0, 0, 0, 0}, acc1 = {0, 0, 0, 0};
                const int nt0 = wid, nt1 = wid + 8;
                #pragma unroll
                for (int ks = 0; ks < 4; ks++) {
                    bf16x8 af = *(const bf16x8*)(Hs2 + l15 * 136 + ks * 32 + q * 8);
                    bf16x8 b0 = *(const bf16x8*)(wsW3 + (size_t)i * 32768 +
                                                 ((nt0 * 4 + ks) * 64 + lane) * 8);
                    bf16x8 b1 = *(const bf16x8*)(wsW3 + (size_t)i * 32768 +
                                                 ((nt1 * 4 + ks) * 64 + lane) * 8);
                    acc0 = __builtin_amdgcn_mfma_f32_16x16x32_bf16(af, b0, acc0, 0, 0, 0);
                    acc1 = __builtin_amdgcn_mfma_f32_16x16x32_bf16(af, b1, acc1, 0, 0, 0);
                }
                #pragma unroll
                for (int r = 0; r < 4; r++) {
                    int mrow = q * 4 + r;
                    if (mrow < BTILE) {
                        int bglob = blk * BTILE + mrow;
                        size_t obase = ((size_t)bglob * 32 + i) * 256;
                        int n0 = nt0 * 16 + l15, n1 = nt1 * 16 + l15;
                        float ne0 = outp[obase + n0];          // NE (prep_ne), read-before-write
                        float ne1 = outp[obase + n1];
                        float v0 = acc0[r] + mb3[i * 256 + n0] + ne0;
                        float v1 = acc1[r] + mb3[i * 256 + n1] + ne1;
                        vals[i * 2048 + mrow * 256 + n0] = f2b(v0);
                        vals[i * 2048 + mrow * 256 + n1] = f2b(v1);
                        if (layer == 2) {
                            outp[obase + n0] = v0;
                            outp[obase + n1] = v1;
                        }
                    }
                }
            }
            __syncthreads();
        }
    }
}

extern "C" void kernel_launch(void* const* d_in, const int* in_sizes, int n_in,
                              void* d_out, int out_size, void* d_ws, size_t ws_size,
                              hipStream_t stream) {
    (void)in_sizes; (void)n_in; (void)out_size; (void)ws_size;
    const float* noise = (const float*)d_in[0];
    const float* edge  = (const float*)d_in[1];
    const float* emb   = (const float*)d_in[2];
    const float* paW   = (const float*)d_in[3];
    const float* pab   = (const float*)d_in[4];
    const float* mW1   = (const float*)d_in[5];
    const float* mb1   = (const float*)d_in[6];
    const float* mW2   = (const float*)d_in[7];
    const float* mb2   = (const float*)d_in[8];
    const float* mW3   = (const float*)d_in[9];
    const float* mb3   = (const float*)d_in[10];
    const float* neW   = (const float*)d_in[11];
    const float* neb   = (const float*)d_in[12];
    float* outp = (float*)d_out;

    float* adjw = (float*)d_ws;
    unsigned short* wsb = (unsigned short*)((char*)d_ws + 4096);
    unsigned short* vals = wsb + ELOFF_VALS;

    prep_w<<<1316, 256, 0, stream>>>(paW, mW1, mW2, mW3, edge, wsb, adjw);
    prep_ne<<<256, 256, 0, stream>>>(noise, neW, neb, outp);
    scm_main<<<NBLK, 512, 0, stream>>>(emb, pab, mb1, mb2, mb3, adjw,
                                       (const __bf16*)wsb, outp, vals);
}

// Round 2
// 770.160 us; speedup vs baseline: 1.3179x; 1.3179x over previous
//
#include <hip/hip_runtime.h>

// ---------------------------------------------------------------------------
// StructuralCausalModel: 3 layers x 32 vars sequential scan, BATCH=512.
// R2: latency-bound fix. pa_W resident in VGPRs; one-stage-ahead register
// prefetch of W1/W2/W3/NE/biases; adjacency via wave-uniform scalar loads
// (kills one barrier/step); rcp-gelu. 64 blocks x 512 thr, BTILE=8.
// ---------------------------------------------------------------------------

typedef __bf16 bf16x8 __attribute__((ext_vector_type(8)));
typedef float  f32x4  __attribute__((ext_vector_type(4)));

#define N_VARS 32
#define D_MODEL 256
#define D_MECH 128
#define BATCH 512
#define NBLK 64
#define BTILE 8

// ws element offsets (bf16 region starts at byte 4096; adjT f32 at byte 0)
#define ELOFF_PA 0
#define ELOFF_W1 65536
#define ELOFF_W2 1114112
#define ELOFF_W3 1638400
#define ELOFF_VALS 2686976
// total bf16 el = 2686976 + 64*65536 = 6881280 -> ws bytes = 4096 + 13762560

__device__ __forceinline__ unsigned short f2b(float f) {
    unsigned u = __float_as_uint(f);
    u += 0x7FFFu + ((u >> 16) & 1u);
    return (unsigned short)(u >> 16);
}
__device__ __forceinline__ float b2f(unsigned u16) {
    return __uint_as_float(u16 << 16);
}

// exact-erf GELU via Abramowitz-Stegun 7.1.26 (|err| <= 1.5e-7); rcp approx ok
__device__ __forceinline__ float gelu_exact(float x) {
    float z  = x * 0.7071067811865476f;
    float az = fabsf(z);
    float t  = __builtin_amdgcn_rcpf(1.0f + 0.3275911f * az);
    float p  = t * (0.254829592f + t * (-0.284496736f + t * (1.421413741f +
               t * (-1.453152027f + t * 1.061405429f))));
    float e  = 1.0f - p * __expf(-z * z);
    float er = (z < 0.0f) ? -e : e;
    return 0.5f * x * (1.0f + er);
}

// ---------------------------------------------------------------------------
// Prep 1: f32->bf16 weights pre-swizzled into MFMA-B fragment order; adjacency
// stored TRANSPOSED: adjT[i*32+v] = sigmoid(2*masked_logits[v][i]).
// B-frag (16x16x32): lane l, elem j -> k = ks*32 + (l>>4)*8 + j, n = nt*16 + (l&15)
// ---------------------------------------------------------------------------
__global__ void prep_w(const float* __restrict__ paW, const float* __restrict__ mW1,
                       const float* __restrict__ mW2, const float* __restrict__ mW3,
                       const float* __restrict__ edge, unsigned short* __restrict__ wsb,
                       float* __restrict__ adjT) {
    int idx = blockIdx.x * 256 + threadIdx.x;
    if (idx < 335872) {
        const float* src; int n, kb, N;
        int f = idx;
        if (f < 8192) {                       // pa_W: 16nt x 8ks
            int nt = f >> 9, ks = (f >> 6) & 7, lane = f & 63;
            n = nt * 16 + (lane & 15); kb = ks * 32 + ((lane >> 4) << 3);
            src = paW; N = 256;
        } else if (f < 139264) {              // m_W1: per var 8nt x 8ks
            int f1 = f - 8192; int var = f1 >> 12; int r = f1 & 4095;
            int nt = r >> 9, ks = (r >> 6) & 7, lane = r & 63;
            n = nt * 16 + (lane & 15); kb = ks * 32 + ((lane >> 4) << 3);
            src = mW1 + var * 32768; N = 128;
        } else if (f < 204800) {              // m_W2: per var 8nt x 4ks
            int f2 = f - 139264; int var = f2 >> 11; int r = f2 & 2047;
            int nt = r >> 8, ks = (r >> 6) & 3, lane = r & 63;
            n = nt * 16 + (lane & 15); kb = ks * 32 + ((lane >> 4) << 3);
            src = mW2 + var * 16384; N = 128;
        } else {                               // m_W3: per var 16nt x 4ks
            int f3 = f - 204800; int var = f3 >> 12; int r = f3 & 4095;
            int nt = r >> 8, ks = (r >> 6) & 3, lane = r & 63;
            n = nt * 16 + (lane & 15); kb = ks * 32 + ((lane >> 4) << 3);
            src = mW3 + var * 32768; N = 256;
        }
        unsigned o[8];
        #pragma unroll
        for (int j = 0; j < 8; j++) o[j] = f2b(src[(kb + j) * N + n]);
        uint4 pk;
        pk.x = o[0] | (o[1] << 16); pk.y = o[2] | (o[3] << 16);
        pk.z = o[4] | (o[5] << 16); pk.w = o[6] | (o[7] << 16);
        *(uint4*)(wsb + (size_t)f * 8) = pk;
    } else if (idx < 336896) {
        int t = idx - 335872; int v = t >> 5; int c = t & 31;
        float x = edge[t];
        float m = (v == c) ? 0.0f : x;        // diag logit masked -> adj diag = 0.5
        adjT[c * 32 + v] = __builtin_amdgcn_rcpf(1.0f + __expf(-2.0f * m));
    }
}

// ---------------------------------------------------------------------------
// Prep 2: NE[b,i,:] = gelu(noise[b,i,:] @ ne_W[i] + ne_b[i]) -> d_out (f32),
// overwritten by the true output at layer 2.
// ---------------------------------------------------------------------------
__global__ void prep_ne(const float* __restrict__ noise, const float* __restrict__ neW,
                        const float* __restrict__ neb, float* __restrict__ outp) {
    int i = blockIdx.x >> 3, g = blockIdx.x & 7, d = threadIdx.x;
    float w[64];
    #pragma unroll
    for (int k = 0; k < 64; k++) w[k] = neW[(i * 64 + k) * 256 + d];
    float bias = neb[i * 256 + d];
    for (int bb = 0; bb < 64; bb++) {
        int b = g * 64 + bb;
        const float* nr = noise + (b * 32 + i) * 64;
        float acc = bias;
        #pragma unroll
        for (int k = 0; k < 64; k++) acc += nr[k] * w[k];
        outp[(b * 32 + i) * 256 + d] = gelu_exact(acc);
    }
}

#define MFMA16(a, b, c) __builtin_amdgcn_mfma_f32_16x16x32_bf16(a, b, c, 0, 0, 0)

// ---------------------------------------------------------------------------
// Main: 64 blocks x 512 threads. Per step: pc (VALU) -> pa -> W1 -> W2 -> W3.
// Weight/bias/NE loads are issued exactly one stage ahead so each stage's
// global latency overlaps the previous stage's compute (barriers drain vmcnt).
// ---------------------------------------------------------------------------
__global__ __launch_bounds__(512) void
scm_main(const float* __restrict__ emb, const float* __restrict__ pab,
         const float* __restrict__ mb1, const float* __restrict__ mb2,
         const float* __restrict__ mb3, const float* __restrict__ adjT,
         const __bf16* __restrict__ wsbf, float* __restrict__ outp,
         unsigned short* __restrict__ valsAll) {
    __shared__ unsigned short Xs[16 * 264];   // pc+emb  (A for pa)
    __shared__ unsigned short X2[16 * 264];   // parent_input (A for W1)
    __shared__ unsigned short Hs1[16 * 136];  // h1 (A for W2)
    __shared__ unsigned short Hs2[16 * 136];  // h2 (A for W3)

    const int tid = threadIdx.x, blk = blockIdx.x;
    unsigned short* vals = valsAll + (size_t)blk * 65536;

    // zero LDS pads + private values (ws is poisoned 0xAA every launch)
    for (int k = tid; k < 16 * 264; k += 512) { Xs[k] = 0; X2[k] = 0; }
    for (int k = tid; k < 16 * 136; k += 512) { Hs1[k] = 0; Hs2[k] = 0; }
    {
        uint4 z; z.x = z.y = z.z = z.w = 0;
        for (int k = tid; k < 8192; k += 512) ((uint4*)vals)[k] = z;
    }

    const int wid = tid >> 6, lane = tid & 63, l15 = lane & 15, q = lane >> 4;
    const int nW = wid * 16 + l15;          // 0..127
    const int n0 = nW, n1 = nW + 128;       // 0..255
    const int d4 = lane << 2;               // pc column group

    // ---- step-invariant: pa_W fragments + pa bias resident in registers ----
    bf16x8 paf0[8], paf1[8];
    #pragma unroll
    for (int ks = 0; ks < 8; ks++) {
        paf0[ks] = *(const bf16x8*)(wsbf + ELOFF_PA + ((wid * 8 + ks) * 64 + lane) * 8);
        paf1[ks] = *(const bf16x8*)(wsbf + ELOFF_PA + (((wid + 8) * 8 + ks) * 64 + lane) * 8);
    }
    const float pb0 = pab[n0], pb1 = pab[n1];
    __syncthreads();

    for (int layer = 0; layer < 3; layer++) {
        for (int i = 0; i < N_VARS; i++) {
            // ---- step-top prefetch (consumed in later stages) ----
            const float* __restrict__ ar = adjT + i * 32;      // wave-uniform -> s_load
            float4 e4 = *(const float4*)(emb + i * 256 + d4);
            float bi1 = mb1[i * 128 + nW];
            float bi2 = mb2[i * 128 + nW];
            float b3a = mb3[i * 256 + n0];
            float b3b = mb3[i * 256 + n1];
            bf16x8 w1f[8];
            #pragma unroll
            for (int ks = 0; ks < 8; ks++)
                w1f[ks] = *(const bf16x8*)(wsbf + ELOFF_W1 + (size_t)i * 32768 +
                                           ((wid * 8 + ks) * 64 + lane) * 8);

            // ---- pc = sum_v adj[v,i]*values[b,v,:]; X = bf16(pc + emb_i) ----
            {
                float a0 = 0.f, a1 = 0.f, a2 = 0.f, a3 = 0.f;
                const unsigned short* vp = vals + wid * 256 + d4;
                #pragma unroll
                for (int v = 0; v < 32; v++) {
                    uint2 u = *(const uint2*)(vp + v * 2048);
                    float s = ar[v];
                    a0 += s * b2f(u.x & 0xFFFFu); a1 += s * b2f(u.x >> 16);
                    a2 += s * b2f(u.y & 0xFFFFu); a3 += s * b2f(u.y >> 16);
                }
                uint2 w;
                w.x = (unsigned)f2b(a0 + e4.x) | ((unsigned)f2b(a1 + e4.y) << 16);
                w.y = (unsigned)f2b(a2 + e4.z) | ((unsigned)f2b(a3 + e4.w) << 16);
                *(uint2*)(Xs + wid * 264 + d4) = w;
            }
            __syncthreads();

            // ---- pa: gelu(X @ pa_W + pa_b); prefetch W2 ----
            bf16x8 w2f[4];
            #pragma unroll
            for (int ks = 0; ks < 4; ks++)
                w2f[ks] = *(const bf16x8*)(wsbf + ELOFF_W2 + (size_t)i * 16384 +
                                           ((wid * 4 + ks) * 64 + lane) * 8);
            {
                f32x4 acc0 = {0, 0, 0, 0}, acc1 = {0, 0, 0, 0};
                #pragma unroll
                for (int ks = 0; ks < 8; ks++) {
                    bf16x8 af = *(const bf16x8*)(Xs + l15 * 264 + ks * 32 + q * 8);
                    acc0 = MFMA16(af, paf0[ks], acc0);
                    acc1 = MFMA16(af, paf1[ks], acc1);
                }
                #pragma unroll
                for (int r = 0; r < 4; r++) {
                    int mrow = q * 4 + r;
                    if (mrow < BTILE) {
                        X2[mrow * 264 + n0] = f2b(gelu_exact(acc0[r] + pb0));
                        X2[mrow * 264 + n1] = f2b(gelu_exact(acc1[r] + pb1));
                    }
                }
            }
            __syncthreads();

            // ---- W1: gelu(X2 @ W1 + b1); prefetch W3 ----
            bf16x8 w3f0[4], w3f1[4];
            #pragma unroll
            for (int ks = 0; ks < 4; ks++) {
                w3f0[ks] = *(const bf16x8*)(wsbf + ELOFF_W3 + (size_t)i * 32768 +
                                            ((wid * 4 + ks) * 64 + lane) * 8);
                w3f1[ks] = *(const bf16x8*)(wsbf + ELOFF_W3 + (size_t)i * 32768 +
                                            (((wid + 8) * 4 + ks) * 64 + lane) * 8);
            }
            {
                f32x4 aa = {0, 0, 0, 0}, ab = {0, 0, 0, 0};
                #pragma unroll
                for (int ks = 0; ks < 8; ks += 2) {
                    bf16x8 af0 = *(const bf16x8*)(X2 + l15 * 264 + ks * 32 + q * 8);
                    bf16x8 af1 = *(const bf16x8*)(X2 + l15 * 264 + (ks + 1) * 32 + q * 8);
                    aa = MFMA16(af0, w1f[ks], aa);
                    ab = MFMA16(af1, w1f[ks + 1], ab);
                }
                #pragma unroll
                for (int r = 0; r < 4; r++) {
                    int mrow = q * 4 + r;
                    if (mrow < BTILE)
                        Hs1[mrow * 136 + nW] = f2b(gelu_exact(aa[r] + ab[r] + bi1));
                }
            }
            __syncthreads();

            // ---- W2: gelu(h1 @ W2 + b2); prefetch NE ----
            float ne0[4], ne1[4];
            #pragma unroll
            for (int r = 0; r < 4; r++) {
                int mrow = q * 4 + r;
                ne0[r] = 0.f; ne1[r] = 0.f;
                if (mrow < BTILE) {
                    size_t obase = ((size_t)(blk * BTILE + mrow) * 32 + i) * 256;
                    ne0[r] = outp[obase + n0];
                    ne1[r] = outp[obase + n1];
                }
            }
            {
                f32x4 acc = {0, 0, 0, 0};
                #pragma unroll
                for (int ks = 0; ks < 4; ks++) {
                    bf16x8 af = *(const bf16x8*)(Hs1 + l15 * 136 + ks * 32 + q * 8);
                    acc = MFMA16(af, w2f[ks], acc);
                }
                #pragma unroll
                for (int r = 0; r < 4; r++) {
                    int mrow = q * 4 + r;
                    if (mrow < BTILE)
                        Hs2[mrow * 136 + nW] = f2b(gelu_exact(acc[r] + bi2));
                }
            }
            __syncthreads();

            // ---- W3: out = h2 @ W3 + b3 + NE; values[:,i] = out ----
            {
                f32x4 acc0 = {0, 0, 0, 0}, acc1 = {0, 0, 0, 0};
                #pragma unroll
                for (int ks = 0; ks < 4; ks++) {
                    bf16x8 af = *(const bf16x8*)(Hs2 + l15 * 136 + ks * 32 + q * 8);
                    acc0 = MFMA16(af, w3f0[ks], acc0);
                    acc1 = MFMA16(af, w3f1[ks], acc1);
                }
                #pragma unroll
                for (int r = 0; r < 4; r++) {
                    int mrow = q * 4 + r;
                    if (mrow < BTILE) {
                        size_t obase = ((size_t)(blk * BTILE + mrow) * 32 + i) * 256;
                        float v0 = acc0[r] + b3a + ne0[r];
                        float v1 = acc1[r] + b3b + ne1[r];
                        vals[i * 2048 + mrow * 256 + n0] = f2b(v0);
                        vals[i * 2048 + mrow * 256 + n1] = f2b(v1);
                        if (layer == 2) {
                            outp[obase + n0] = v0;
                            outp[obase + n1] = v1;
                        }
                    }
                }
            }
            __syncthreads();
        }
    }
}

extern "C" void kernel_launch(void* const* d_in, const int* in_sizes, int n_in,
                              void* d_out, int out_size, void* d_ws, size_t ws_size,
                              hipStream_t stream) {
    (void)in_sizes; (void)n_in; (void)out_size; (void)ws_size;
    const float* noise = (const float*)d_in[0];
    const float* edge  = (const float*)d_in[1];
    const float* emb   = (const float*)d_in[2];
    const float* paW   = (const float*)d_in[3];
    const float* pab   = (const float*)d_in[4];
    const float* mW1   = (const float*)d_in[5];
    const float* mb1   = (const float*)d_in[6];
    const float* mW2   = (const float*)d_in[7];
    const float* mb2   = (const float*)d_in[8];
    const float* mW3   = (const float*)d_in[9];
    const float* mb3   = (const float*)d_in[10];
    const float* neW   = (const float*)d_in[11];
    const float* neb   = (const float*)d_in[12];
    float* outp = (float*)d_out;

    float* adjT = (float*)d_ws;
    unsigned short* wsb = (unsigned short*)((char*)d_ws + 4096);
    unsigned short* vals = wsb + ELOFF_VALS;

    prep_w<<<1316, 256, 0, stream>>>(paW, mW1, mW2, mW3, edge, wsb, adjT);
    prep_ne<<<256, 256, 0, stream>>>(noise, neW, neb, outp);
    scm_main<<<NBLK, 512, 0, stream>>>(emb, pab, mb1, mb2, mb3, adjT,
                                       (const __bf16*)wsb, outp, vals);
}

// Round 3
// 580.052 us; speedup vs baseline: 1.7499x; 1.3277x over previous
//
#include <hip/hip_runtime.h>

// ---------------------------------------------------------------------------
// StructuralCausalModel: 3 layers x 32 vars sequential scan, BATCH=512.
// R3: (a) CK-style lgkm-only barriers so global weight prefetches stay in
// flight across stage barriers (no vmcnt(0) drain); (b) values buffer moved
// to LDS (156.7 KB static total) -- all cross-wave deps are now LDS-only,
// which is what makes (a) correct; (c) all weight/NE prefetch at step top;
// (d) merged prep kernel. 64 blocks x 512 thr, BTILE=8.
// ---------------------------------------------------------------------------

typedef __bf16 bf16x8 __attribute__((ext_vector_type(8)));
typedef float  f32x4  __attribute__((ext_vector_type(4)));

#define N_VARS 32
#define D_MODEL 256
#define D_MECH 128
#define BATCH 512
#define NBLK 64
#define BTILE 8

// ws element offsets (bf16 region starts at byte 4096; adjT f32 at byte 0)
#define ELOFF_PA 0
#define ELOFF_W1 65536
#define ELOFF_W2 1114112
#define ELOFF_W3 1638400
// total bf16 el = 2686976 -> ws bytes = 4096 + 5373952

__device__ __forceinline__ unsigned short f2b(float f) {
    unsigned u = __float_as_uint(f);
    u += 0x7FFFu + ((u >> 16) & 1u);
    return (unsigned short)(u >> 16);
}
__device__ __forceinline__ float b2f(unsigned u16) {
    return __uint_as_float(u16 << 16);
}

// lgkm-only barrier (composable_kernel block_sync_lds pattern): LDS producer
// ordering is enforced, but global loads in flight are NOT drained.
__device__ __forceinline__ void bar_lds() {
    asm volatile("s_waitcnt lgkmcnt(0)\n\ts_barrier" ::: "memory");
}

// exact-erf GELU via Abramowitz-Stegun 7.1.26 (|err| <= 1.5e-7)
__device__ __forceinline__ float gelu_exact(float x) {
    float z  = x * 0.7071067811865476f;
    float az = fabsf(z);
    float t  = __builtin_amdgcn_rcpf(1.0f + 0.3275911f * az);
    float p  = t * (0.254829592f + t * (-0.284496736f + t * (1.421413741f +
               t * (-1.453152027f + t * 1.061405429f))));
    float e  = 1.0f - p * __expf(-z * z);
    float er = (z < 0.0f) ? -e : e;
    return 0.5f * x * (1.0f + er);
}

// ---------------------------------------------------------------------------
// Merged prep: blocks [0,1316) = weight f32->bf16 MFMA-B-frag swizzle + adjT;
// blocks [1316,1828) = noise encoder NE -> d_out (f32, overwritten at layer 2).
// B-frag (16x16x32): lane l, elem j -> k = ks*32 + (l>>4)*8 + j, n = nt*16 + (l&15)
// ---------------------------------------------------------------------------
__global__ void prep_all(const float* __restrict__ paW, const float* __restrict__ mW1,
                         const float* __restrict__ mW2, const float* __restrict__ mW3,
                         const float* __restrict__ edge, unsigned short* __restrict__ wsb,
                         float* __restrict__ adjT,
                         const float* __restrict__ noise, const float* __restrict__ neW,
                         const float* __restrict__ neb, float* __restrict__ outp) {
    int blk = blockIdx.x;
    if (blk < 1316) {
        int idx = blk * 256 + threadIdx.x;
        if (idx < 335872) {
            const float* src; int n, kb, N;
            int f = idx;
            if (f < 8192) {                       // pa_W: 16nt x 8ks
                int nt = f >> 9, ks = (f >> 6) & 7, lane = f & 63;
                n = nt * 16 + (lane & 15); kb = ks * 32 + ((lane >> 4) << 3);
                src = paW; N = 256;
            } else if (f < 139264) {              // m_W1: per var 8nt x 8ks
                int f1 = f - 8192; int var = f1 >> 12; int r = f1 & 4095;
                int nt = r >> 9, ks = (r >> 6) & 7, lane = r & 63;
                n = nt * 16 + (lane & 15); kb = ks * 32 + ((lane >> 4) << 3);
                src = mW1 + var * 32768; N = 128;
            } else if (f < 204800) {              // m_W2: per var 8nt x 4ks
                int f2 = f - 139264; int var = f2 >> 11; int r = f2 & 2047;
                int nt = r >> 8, ks = (r >> 6) & 3, lane = r & 63;
                n = nt * 16 + (lane & 15); kb = ks * 32 + ((lane >> 4) << 3);
                src = mW2 + var * 16384; N = 128;
            } else {                               // m_W3: per var 16nt x 4ks
                int f3 = f - 204800; int var = f3 >> 12; int r = f3 & 4095;
                int nt = r >> 8, ks = (r >> 6) & 3, lane = r & 63;
                n = nt * 16 + (lane & 15); kb = ks * 32 + ((lane >> 4) << 3);
                src = mW3 + var * 32768; N = 256;
            }
            unsigned o[8];
            #pragma unroll
            for (int j = 0; j < 8; j++) o[j] = f2b(src[(kb + j) * N + n]);
            uint4 pk;
            pk.x = o[0] | (o[1] << 16); pk.y = o[2] | (o[3] << 16);
            pk.z = o[4] | (o[5] << 16); pk.w = o[6] | (o[7] << 16);
            *(uint4*)(wsb + (size_t)f * 8) = pk;
        } else if (idx < 336896) {
            int t = idx - 335872; int v = t >> 5; int c = t & 31;
            float x = edge[t];
            float m = (v == c) ? 0.0f : x;        // diag logit masked -> adj diag = 0.5
            adjT[c * 32 + v] = __builtin_amdgcn_rcpf(1.0f + __expf(-2.0f * m));
        }
    } else {
        int sb = blk - 1316;                      // 512 sub-blocks: 32 vars x 16 groups
        int i = sb >> 4, g = sb & 15, d = threadIdx.x;
        float w[64];
        #pragma unroll
        for (int k = 0; k < 64; k++) w[k] = neW[(i * 64 + k) * 256 + d];
        float bias = neb[i * 256 + d];
        for (int bb = 0; bb < 32; bb++) {
            int b = g * 32 + bb;
            const float* nr = noise + (b * 32 + i) * 64;
            float acc = bias;
            #pragma unroll
            for (int k = 0; k < 64; k++) acc += nr[k] * w[k];
            outp[(b * 32 + i) * 256 + d] = gelu_exact(acc);
        }
    }
}

#define MFMA16(a, b, c) __builtin_amdgcn_mfma_f32_16x16x32_bf16(a, b, c, 0, 0, 0)

// ---------------------------------------------------------------------------
// Main: 64 blocks x 512 threads, 1 block/CU (LDS-bound: 156.7 KB).
// Per step: prefetch-everything -> pc (LDS+VALU) -> pa -> W1 -> W2 -> W3.
// All barriers are lgkm-only; weight loads ride across them and are waited
// on only at their consuming MFMA (compiler vmcnt(N)).
// ---------------------------------------------------------------------------
__global__ __launch_bounds__(512) void
scm_main(const float* __restrict__ emb, const float* __restrict__ pab,
         const float* __restrict__ mb1, const float* __restrict__ mb2,
         const float* __restrict__ mb3, const float* __restrict__ adjT,
         const __bf16* __restrict__ wsbf, float* __restrict__ outp) {
    __shared__ unsigned short valsS[32 * 2048];   // [var][b 0..7][256 d]  128 KB
    __shared__ unsigned short Xs[16 * 264];       // pc+emb  (A for pa)
    __shared__ unsigned short X2[16 * 264];       // parent_input (A for W1)
    __shared__ unsigned short Hs1[16 * 136];      // h1 (A for W2)
    __shared__ unsigned short Hs2[16 * 136];      // h2 (A for W3)

    const int tid = threadIdx.x, blk = blockIdx.x;

    // zero LDS (MFMA M-pad rows 8..15 stay zero forever; vals starts zero)
    for (int k = tid; k < 16 * 264; k += 512) { Xs[k] = 0; X2[k] = 0; }
    for (int k = tid; k < 16 * 136; k += 512) { Hs1[k] = 0; Hs2[k] = 0; }
    {
        uint4 z; z.x = z.y = z.z = z.w = 0;
        for (int k = tid; k < 8192; k += 512) ((uint4*)valsS)[k] = z;
    }

    const int wid = tid >> 6, lane = tid & 63, l15 = lane & 15, q = lane >> 4;
    const int nW = wid * 16 + l15;          // 0..127
    const int n0 = nW, n1 = nW + 128;       // 0..255
    const int d4 = lane << 2;               // pc column group

    // step-invariant: pa_W fragments + pa bias resident in registers
    bf16x8 paf0[8], paf1[8];
    #pragma unroll
    for (int ks = 0; ks < 8; ks++) {
        paf0[ks] = *(const bf16x8*)(wsbf + ELOFF_PA + ((wid * 8 + ks) * 64 + lane) * 8);
        paf1[ks] = *(const bf16x8*)(wsbf + ELOFF_PA + (((wid + 8) * 8 + ks) * 64 + lane) * 8);
    }
    const float pb0 = pab[n0], pb1 = pab[n1];
    bar_lds();

    for (int layer = 0; layer < 3; layer++) {
        for (int i = 0; i < N_VARS; i++) {
            // ---- step-top prefetch: ALL globals for this step ----
            const float* __restrict__ ar = adjT + i * 32;      // wave-uniform s_load
            float4 e4 = *(const float4*)(emb + i * 256 + d4);
            float bi1 = mb1[i * 128 + nW];
            float bi2 = mb2[i * 128 + nW];
            float b3a = mb3[i * 256 + n0];
            float b3b = mb3[i * 256 + n1];
            bf16x8 w1f[8];
            #pragma unroll
            for (int ks = 0; ks < 8; ks++)
                w1f[ks] = *(const bf16x8*)(wsbf + ELOFF_W1 + (size_t)i * 32768 +
                                           ((wid * 8 + ks) * 64 + lane) * 8);
            bf16x8 w2f[4];
            #pragma unroll
            for (int ks = 0; ks < 4; ks++)
                w2f[ks] = *(const bf16x8*)(wsbf + ELOFF_W2 + (size_t)i * 16384 +
                                           ((wid * 4 + ks) * 64 + lane) * 8);
            bf16x8 w3f0[4], w3f1[4];
            #pragma unroll
            for (int ks = 0; ks < 4; ks++) {
                w3f0[ks] = *(const bf16x8*)(wsbf + ELOFF_W3 + (size_t)i * 32768 +
                                            ((wid * 4 + ks) * 64 + lane) * 8);
                w3f1[ks] = *(const bf16x8*)(wsbf + ELOFF_W3 + (size_t)i * 32768 +
                                            (((wid + 8) * 4 + ks) * 64 + lane) * 8);
            }
            float ne0[4], ne1[4];
            #pragma unroll
            for (int r = 0; r < 4; r++) {
                int mrow = q * 4 + r;
                ne0[r] = 0.f; ne1[r] = 0.f;
                if (mrow < BTILE) {
                    size_t ob = ((size_t)(blk * BTILE + mrow) * 32 + i) * 256;
                    ne0[r] = outp[ob + n0];
                    ne1[r] = outp[ob + n1];
                }
            }

            // ---- pc = sum_v adj[v,i]*vals[b,v,:]; X = bf16(pc + emb_i) ----
            {
                float a0 = 0.f, a1 = 0.f, a2 = 0.f, a3 = 0.f;
                const unsigned short* vp = valsS + wid * 256 + d4;
                #pragma unroll
                for (int v = 0; v < 32; v++) {
                    uint2 u = *(const uint2*)(vp + v * 2048);
                    float s = ar[v];
                    a0 += s * b2f(u.x & 0xFFFFu); a1 += s * b2f(u.x >> 16);
                    a2 += s * b2f(u.y & 0xFFFFu); a3 += s * b2f(u.y >> 16);
                }
                uint2 w;
                w.x = (unsigned)f2b(a0 + e4.x) | ((unsigned)f2b(a1 + e4.y) << 16);
                w.y = (unsigned)f2b(a2 + e4.z) | ((unsigned)f2b(a3 + e4.w) << 16);
                *(uint2*)(Xs + wid * 264 + d4) = w;
            }
            bar_lds();

            // ---- pa: gelu(X @ pa_W + pa_b) ----
            {
                f32x4 acc0 = {0, 0, 0, 0}, acc1 = {0, 0, 0, 0};
                #pragma unroll
                for (int ks = 0; ks < 8; ks++) {
                    bf16x8 af = *(const bf16x8*)(Xs + l15 * 264 + ks * 32 + q * 8);
                    acc0 = MFMA16(af, paf0[ks], acc0);
                    acc1 = MFMA16(af, paf1[ks], acc1);
                }
                #pragma unroll
                for (int r = 0; r < 4; r++) {
                    int mrow = q * 4 + r;
                    if (mrow < BTILE) {
                        X2[mrow * 264 + n0] = f2b(gelu_exact(acc0[r] + pb0));
                        X2[mrow * 264 + n1] = f2b(gelu_exact(acc1[r] + pb1));
                    }
                }
            }
            bar_lds();

            // ---- W1: gelu(X2 @ W1 + b1) ----
            {
                f32x4 aa = {0, 0, 0, 0}, ab = {0, 0, 0, 0};
                #pragma unroll
                for (int ks = 0; ks < 8; ks += 2) {
                    bf16x8 af0 = *(const bf16x8*)(X2 + l15 * 264 + ks * 32 + q * 8);
                    bf16x8 af1 = *(const bf16x8*)(X2 + l15 * 264 + (ks + 1) * 32 + q * 8);
                    aa = MFMA16(af0, w1f[ks], aa);
                    ab = MFMA16(af1, w1f[ks + 1], ab);
                }
                #pragma unroll
                for (int r = 0; r < 4; r++) {
                    int mrow = q * 4 + r;
                    if (mrow < BTILE)
                        Hs1[mrow * 136 + nW] = f2b(gelu_exact(aa[r] + ab[r] + bi1));
                }
            }
            bar_lds();

            // ---- W2: gelu(h1 @ W2 + b2) ----
            {
                f32x4 acc = {0, 0, 0, 0};
                #pragma unroll
                for (int ks = 0; ks < 4; ks++) {
                    bf16x8 af = *(const bf16x8*)(Hs1 + l15 * 136 + ks * 32 + q * 8);
                    acc = MFMA16(af, w2f[ks], acc);
                }
                #pragma unroll
                for (int r = 0; r < 4; r++) {
                    int mrow = q * 4 + r;
                    if (mrow < BTILE)
                        Hs2[mrow * 136 + nW] = f2b(gelu_exact(acc[r] + bi2));
                }
            }
            bar_lds();

            // ---- W3: out = h2 @ W3 + b3 + NE; vals[:,i] = out (LDS) ----
            {
                f32x4 acc0 = {0, 0, 0, 0}, acc1 = {0, 0, 0, 0};
                #pragma unroll
                for (int ks = 0; ks < 4; ks++) {
                    bf16x8 af = *(const bf16x8*)(Hs2 + l15 * 136 + ks * 32 + q * 8);
                    acc0 = MFMA16(af, w3f0[ks], acc0);
                    acc1 = MFMA16(af, w3f1[ks], acc1);
                }
                #pragma unroll
                for (int r = 0; r < 4; r++) {
                    int mrow = q * 4 + r;
                    if (mrow < BTILE) {
                        float v0 = acc0[r] + b3a + ne0[r];
                        float v1 = acc1[r] + b3b + ne1[r];
                        valsS[i * 2048 + mrow * 256 + n0] = f2b(v0);
                        valsS[i * 2048 + mrow * 256 + n1] = f2b(v1);
                        if (layer == 2) {
                            size_t ob = ((size_t)(blk * BTILE + mrow) * 32 + i) * 256;
                            outp[ob + n0] = v0;
                            outp[ob + n1] = v1;
                        }
                    }
                }
            }
            bar_lds();
        }
    }
}

extern "C" void kernel_launch(void* const* d_in, const int* in_sizes, int n_in,
                              void* d_out, int out_size, void* d_ws, size_t ws_size,
                              hipStream_t stream) {
    (void)in_sizes; (void)n_in; (void)out_size; (void)ws_size;
    const float* noise = (const float*)d_in[0];
    const float* edge  = (const float*)d_in[1];
    const float* emb   = (const float*)d_in[2];
    const float* paW   = (const float*)d_in[3];
    const float* pab   = (const float*)d_in[4];
    const float* mW1   = (const float*)d_in[5];
    const float* mb1   = (const float*)d_in[6];
    const float* mW2   = (const float*)d_in[7];
    const float* mb2   = (const float*)d_in[8];
    const float* mW3   = (const float*)d_in[9];
    const float* mb3   = (const float*)d_in[10];
    const float* neW   = (const float*)d_in[11];
    const float* neb   = (const float*)d_in[12];
    float* outp = (float*)d_out;

    float* adjT = (float*)d_ws;
    unsigned short* wsb = (unsigned short*)((char*)d_ws + 4096);

    prep_all<<<1828, 256, 0, stream>>>(paW, mW1, mW2, mW3, edge, wsb, adjT,
                                       noise, neW, neb, outp);
    scm_main<<<NBLK, 512, 0, stream>>>(emb, pab, mb1, mb2, mb3, adjT,
                                       (const __bf16*)wsb, outp);
}